// Round 1
// baseline (335.647 us; speedup 1.0000x reference)
//
#include <hip/hip_runtime.h>

#define N_TOK 4096
#define C_DIM 512
#define NH    8
#define DH    64
#define CPG   16
#define EPS   1e-5f
#define ATT_SCALE 0.125f

typedef __attribute__((ext_vector_type(8))) __bf16 bf16x8;
typedef __attribute__((ext_vector_type(4))) float  f32x4;
using u16 = unsigned short;
using u32 = unsigned int;

__device__ __forceinline__ u16 f2bf(float f){
  u32 x = __builtin_bit_cast(u32, f);
  x += 0x7fffu + ((x>>16)&1u);
  return (u16)(x>>16);
}

// ---------------- fp32 -> bf16 convert (vector x4) ----------------
__global__ __launch_bounds__(256) void k_cvt(const float* __restrict__ src,
                                             u16* __restrict__ dst, int n4){
  int i = blockIdx.x*256 + threadIdx.x;
  if (i < n4){
    float4 v = ((const float4*)src)[i];
    ushort4 o; o.x=f2bf(v.x); o.y=f2bf(v.y); o.z=f2bf(v.z); o.w=f2bf(v.w);
    ((ushort4*)dst)[i] = o;
  }
}

// ---------------- GroupNorm + transpose to X[n][c] bf16 ----------------
__global__ __launch_bounds__(256) void k_gn(const float* __restrict__ x,
      const float* __restrict__ gamma, const float* __restrict__ beta,
      u16* __restrict__ X){
  int g = blockIdx.x;             // 32 groups
  int t = threadIdx.x;            // 256 threads
  const float* gx = x + (size_t)g*CPG*N_TOK;     // 65536 contiguous floats
  float s = 0.f, ss = 0.f;
  const float4* gx4 = (const float4*)gx;
  #pragma unroll 4
  for (int k=0;k<64;k++){
    float4 v = gx4[t + k*256];
    s  += v.x+v.y+v.z+v.w;
    ss += v.x*v.x+v.y*v.y+v.z*v.z+v.w*v.w;
  }
  for (int m=1;m<64;m<<=1){ s += __shfl_xor(s,m); ss += __shfl_xor(ss,m); }
  __shared__ float rs[4], rss[4], stat[2];
  int w = t>>6, lane = t&63;
  if (lane==0){ rs[w]=s; rss[w]=ss; }
  __syncthreads();
  if (t==0){
    float S=rs[0]+rs[1]+rs[2]+rs[3], SS=rss[0]+rss[1]+rss[2]+rss[3];
    float mean = S*(1.f/65536.f);
    float var  = SS*(1.f/65536.f) - mean*mean;
    stat[0]=mean; stat[1]=rsqrtf(var+EPS);
  }
  __syncthreads();
  float mean=stat[0], rstd=stat[1];
  int c0 = w*4;
  float ga[4], be[4];
  #pragma unroll
  for (int j=0;j<4;j++){
    float gm = gamma[g*CPG+c0+j];
    ga[j] = gm*rstd;
    be[j] = beta[g*CPG+c0+j] - mean*rstd*gm;
  }
  for (int n0=0;n0<N_TOK;n0+=64){
    int n = n0 + lane;
    float v0 = gx[(size_t)(c0+0)*N_TOK + n]*ga[0]+be[0];
    float v1 = gx[(size_t)(c0+1)*N_TOK + n]*ga[1]+be[1];
    float v2 = gx[(size_t)(c0+2)*N_TOK + n]*ga[2]+be[2];
    float v3 = gx[(size_t)(c0+3)*N_TOK + n]*ga[3]+be[3];
    ushort4 o; o.x=f2bf(v0); o.y=f2bf(v1); o.z=f2bf(v2); o.w=f2bf(v3);
    *(ushort4*)&X[(size_t)n*C_DIM + g*CPG + c0] = o;
  }
}

// ---------------- NT GEMM: C[m][n] = A[m][:] . B[n][:], K=512, bf16 out ----------------
// grid (M/64, Nout/64), block 256 (4 waves x 16 rows)
__global__ __launch_bounds__(256) void k_gemm_nt(const u16* __restrict__ A,
      const u16* __restrict__ B, u16* __restrict__ Cout, int Nout){
  int m0 = blockIdx.x*64, n0 = blockIdx.y*64;
  int t = threadIdx.x, w = t>>6, l = t&63, lr = l&15, li = l>>4;
  f32x4 acc[4] = {};
  const u16* Ap = A + (size_t)(m0 + w*16 + lr)*512 + li*8;
  const u16* Bp = B + (size_t)(n0 + lr)*512 + li*8;
  #pragma unroll
  for (int c=0;c<16;c++){
    bf16x8 a = *(const bf16x8*)(Ap + c*32);
    #pragma unroll
    for (int T=0;T<4;T++){
      bf16x8 b = *(const bf16x8*)(Bp + (size_t)T*16*512 + c*32);
      acc[T] = __builtin_amdgcn_mfma_f32_16x16x32_bf16(a, b, acc[T], 0,0,0);
    }
  }
  #pragma unroll
  for (int T=0;T<4;T++){
    #pragma unroll
    for (int j=0;j<4;j++){
      int mm = m0 + w*16 + li*4 + j;
      int nn = n0 + T*16 + lr;
      Cout[(size_t)mm*Nout + nn] = f2bf(acc[T][j]);
    }
  }
}

// ---------------- Flash attention: 1 head x 64 q-rows per block ----------------
__global__ __launch_bounds__(256) void k_attn(const u16* __restrict__ Q,
      const u16* __restrict__ K, const u16* __restrict__ V, u16* __restrict__ O){
  __shared__ u16 Kl[64*64];    // [kk][d]  row stride 128B, XOR-swizzled
  __shared__ u16 Vt[64*64];    // [d][kk]  row stride 128B, XOR-swizzled
  __shared__ u16 Pl[4*16*64];  // per-wave P tile [q][kk]
  int h  = blockIdx.y;
  int q0 = blockIdx.x*64;
  int t = threadIdx.x, w = t>>6, l = t&63, lr = l&15, li = l>>4;
  char* Klb=(char*)Kl; char* Vtb=(char*)Vt; char* Plb=(char*)Pl;

  const u16* Qp = Q + (size_t)(q0 + w*16 + lr)*512 + h*64 + li*8;
  bf16x8 qa0 = *(const bf16x8*)(Qp);
  bf16x8 qa1 = *(const bf16x8*)(Qp + 32);

  f32x4 acc[4] = {};
  float mrun[4] = {-1e30f,-1e30f,-1e30f,-1e30f};
  float lrun[4] = {0.f,0.f,0.f,0.f};

  for (int kb=0; kb<64; kb++){
    __syncthreads();
    // stage K tile [64][64]
    #pragma unroll
    for (int rep=0;rep<2;rep++){
      int idx = t + rep*256;          // 0..511
      int kk = idx>>3, seg = idx&7;
      uint4 v = *(const uint4*)(K + (size_t)(kb*64+kk)*512 + h*64 + seg*8);
      *(uint4*)(Klb + kk*128 + ((seg*16) ^ ((kk&7)<<4))) = v;
    }
    // stage V transposed -> Vt[d][kk]
    #pragma unroll
    for (int rep=0;rep<2;rep++){
      int idx = t + rep*256;
      int kk = idx&63, d0 = (idx>>6)*8;
      union { uint4 v; u16 e[8]; } u;
      u.v = *(const uint4*)(V + (size_t)(kb*64+kk)*512 + h*64 + d0);
      #pragma unroll
      for (int j=0;j<8;j++){
        int d = d0+j;
        *(u16*)(Vtb + d*128 + ((kk*2) ^ ((d&7)<<4))) = u.e[j];
      }
    }
    __syncthreads();

    // S = Q K^T  (wave's 16 q-rows x 64 keys)
    f32x4 s[4] = {};
    #pragma unroll
    for (int T=0;T<4;T++){
      int row = T*16 + lr;
      int swz = (row&7)<<4;
      bf16x8 b0 = *(const bf16x8*)(Klb + row*128 + ((li*16     ) ^ swz));
      bf16x8 b1 = *(const bf16x8*)(Klb + row*128 + ((li*16 + 64) ^ swz));
      s[T] = __builtin_amdgcn_mfma_f32_16x16x32_bf16(qa0, b0, s[T], 0,0,0);
      s[T] = __builtin_amdgcn_mfma_f32_16x16x32_bf16(qa1, b1, s[T], 0,0,0);
    }
    #pragma unroll
    for (int T=0;T<4;T++) s[T] *= ATT_SCALE;

    // online softmax per output row j (rows q = li*4+j)
    #pragma unroll
    for (int j=0;j<4;j++){
      float tm = fmaxf(fmaxf(s[0][j],s[1][j]), fmaxf(s[2][j],s[3][j]));
      tm = fmaxf(tm, __shfl_xor(tm,1));
      tm = fmaxf(tm, __shfl_xor(tm,2));
      tm = fmaxf(tm, __shfl_xor(tm,4));
      tm = fmaxf(tm, __shfl_xor(tm,8));
      float mnew = fmaxf(mrun[j], tm);
      float fac  = __expf(mrun[j]-mnew);
      float p0=__expf(s[0][j]-mnew), p1=__expf(s[1][j]-mnew);
      float p2=__expf(s[2][j]-mnew), p3=__expf(s[3][j]-mnew);
      float ps = p0+p1+p2+p3;
      ps += __shfl_xor(ps,1); ps += __shfl_xor(ps,2);
      ps += __shfl_xor(ps,4); ps += __shfl_xor(ps,8);
      lrun[j] = lrun[j]*fac + ps;
      mrun[j] = mnew;
      #pragma unroll
      for (int T=0;T<4;T++) acc[T][j] *= fac;
      int prow = li*4 + j;
      u32 base = w*2048 + prow*128;
      int swz = (prow&7)<<4;
      *(u16*)(Plb + base + (((lr   )*2) ^ swz)) = f2bf(p0);
      *(u16*)(Plb + base + (((lr+16)*2) ^ swz)) = f2bf(p1);
      *(u16*)(Plb + base + (((lr+32)*2) ^ swz)) = f2bf(p2);
      *(u16*)(Plb + base + (((lr+48)*2) ^ swz)) = f2bf(p3);
    }

    // acc += P @ V   (A = P from LDS, B = V^T rows from Vt)
    #pragma unroll
    for (int c=0;c<2;c++){
      int pswz = (lr&7)<<4;
      bf16x8 pa = *(const bf16x8*)(Plb + w*2048 + lr*128 + ((li*16 + c*64) ^ pswz));
      #pragma unroll
      for (int T=0;T<4;T++){
        int vrow = T*16 + lr;
        int vswz = (vrow&7)<<4;
        bf16x8 vb = *(const bf16x8*)(Vtb + vrow*128 + ((li*16 + c*64) ^ vswz));
        acc[T] = __builtin_amdgcn_mfma_f32_16x16x32_bf16(pa, vb, acc[T], 0,0,0);
      }
    }
  }

  // epilogue: O[q][h*64+d] = acc / l
  #pragma unroll
  for (int j=0;j<4;j++){
    float inv = 1.f/lrun[j];
    #pragma unroll
    for (int T=0;T<4;T++){
      int r  = q0 + w*16 + li*4 + j;
      int cc = h*64 + T*16 + lr;
      O[(size_t)r*512 + cc] = f2bf(acc[T][j]*inv);
    }
  }
}

// ---------------- out-proj (computed transposed: y^T[c][n]) + bias + residual ----------------
// grid (512/64, 4096/64), block 256
__global__ __launch_bounds__(256) void k_oproj(const u16* __restrict__ Wo,
      const u16* __restrict__ Ob, const float* __restrict__ bo,
      const float* __restrict__ res, float* __restrict__ out){
  int c0 = blockIdx.x*64, n0 = blockIdx.y*64;
  int t = threadIdx.x, w = t>>6, l = t&63, lr = l&15, li = l>>4;
  f32x4 acc[4] = {};
  const u16* Ap = Wo + (size_t)(c0 + w*16 + lr)*512 + li*8;
  const u16* Bp = Ob + (size_t)(n0 + lr)*512 + li*8;
  #pragma unroll
  for (int c=0;c<16;c++){
    bf16x8 a = *(const bf16x8*)(Ap + c*32);
    #pragma unroll
    for (int T=0;T<4;T++){
      bf16x8 b = *(const bf16x8*)(Bp + (size_t)T*16*512 + c*32);
      acc[T] = __builtin_amdgcn_mfma_f32_16x16x32_bf16(a, b, acc[T], 0,0,0);
    }
  }
  #pragma unroll
  for (int j=0;j<4;j++){
    int cc = c0 + w*16 + li*4 + j;
    float bias = bo[cc];
    #pragma unroll
    for (int T=0;T<4;T++){
      int nn = n0 + T*16 + lr;
      size_t off = (size_t)cc*4096 + nn;
      out[off] = acc[T][j] + bias + res[off];
    }
  }
}

extern "C" void kernel_launch(void* const* d_in, const int* in_sizes, int n_in,
                              void* d_out, int out_size, void* d_ws, size_t ws_size,
                              hipStream_t stream){
  (void)in_sizes; (void)n_in; (void)out_size; (void)ws_size;
  const float* hs    = (const float*)d_in[0];
  const float* gamma = (const float*)d_in[1];
  const float* beta  = (const float*)d_in[2];
  const float* wq    = (const float*)d_in[3];
  const float* wk    = (const float*)d_in[4];
  const float* wv    = (const float*)d_in[5];
  const float* wo    = (const float*)d_in[6];
  const float* bo    = (const float*)d_in[7];
  float* out = (float*)d_out;

  u16* X   = (u16*)d_ws;               // 4096*512
  u16* Qb  = X   + (size_t)4096*512;
  u16* Kb  = Qb  + (size_t)4096*512;
  u16* Vb  = Kb  + (size_t)4096*512;
  u16* Ob  = Vb  + (size_t)4096*512;
  u16* wqb = Ob  + (size_t)4096*512;
  u16* wkb = wqb + (size_t)512*512;
  u16* wvb = wkb + (size_t)512*512;
  u16* wob = wvb + (size_t)512*512;

  k_cvt<<<256,256,0,stream>>>(wq, wqb, 65536);
  k_cvt<<<256,256,0,stream>>>(wk, wkb, 65536);
  k_cvt<<<256,256,0,stream>>>(wv, wvb, 65536);
  k_cvt<<<256,256,0,stream>>>(wo, wob, 65536);
  k_gn<<<32,256,0,stream>>>(hs, gamma, beta, X);
  dim3 gg(64, 8);
  k_gemm_nt<<<gg,256,0,stream>>>(X, wqb, Qb, 512);
  k_gemm_nt<<<gg,256,0,stream>>>(X, wkb, Kb, 512);
  k_gemm_nt<<<gg,256,0,stream>>>(X, wvb, Vb, 512);
  dim3 ga(64, 8);
  k_attn<<<ga,256,0,stream>>>(Qb, Kb, Vb, Ob);
  dim3 go(8, 64);
  k_oproj<<<go,256,0,stream>>>(wob, Ob, bo, hs, out);
}

// Round 2
// 318.943 us; speedup vs baseline: 1.0524x; 1.0524x over previous
//
#include <hip/hip_runtime.h>

#define N_TOK 4096
#define C_DIM 512
#define NH    8
#define DH    64
#define EPS   1e-5f

typedef __attribute__((ext_vector_type(8))) __bf16 bf16x8;
typedef __attribute__((ext_vector_type(4))) float  f32x4;
using u16 = unsigned short;
using u32 = unsigned int;

__device__ __forceinline__ u16 f2bf(float f){
  u32 x = __builtin_bit_cast(u32, f);
  x += 0x7fffu + ((x>>16)&1u);
  return (u16)(x>>16);
}

// ---------------- fp32 -> bf16 convert, all 4 weight mats in one launch ----------------
__global__ __launch_bounds__(256) void k_cvt4(const float* __restrict__ s0,
      const float* __restrict__ s1, const float* __restrict__ s2,
      const float* __restrict__ s3, u16* __restrict__ d0, u16* __restrict__ d1,
      u16* __restrict__ d2, u16* __restrict__ d3){
  int b = blockIdx.x >> 8;                   // 0..3 which matrix
  int i = (blockIdx.x & 255)*256 + threadIdx.x;
  const float* s = b==0?s0 : b==1?s1 : b==2?s2 : s3;
  u16*         d = b==0?d0 : b==1?d1 : b==2?d2 : d3;
  float4 v = ((const float4*)s)[i];
  ushort4 o; o.x=f2bf(v.x); o.y=f2bf(v.y); o.z=f2bf(v.z); o.w=f2bf(v.w);
  ((ushort4*)d)[i] = o;
}

// ---------------- GroupNorm stats: grid (32 groups, 8 parts) ----------------
__global__ __launch_bounds__(256) void k_gn_stats(const float* __restrict__ x,
                                                  float* __restrict__ pstat){
  int g = blockIdx.x, p = blockIdx.y, t = threadIdx.x;
  const float4* gx4 = (const float4*)(x + (size_t)g*16*N_TOK) + (size_t)p*2048;
  float s=0.f, ss=0.f;
  #pragma unroll
  for (int k=0;k<8;k++){
    float4 v = gx4[t + k*256];
    s  += v.x+v.y+v.z+v.w;
    ss += v.x*v.x+v.y*v.y+v.z*v.z+v.w*v.w;
  }
  for (int m=1;m<64;m<<=1){ s += __shfl_xor(s,m); ss += __shfl_xor(ss,m); }
  __shared__ float rs[4], rss[4];
  int w=t>>6, lane=t&63;
  if (lane==0){ rs[w]=s; rss[w]=ss; }
  __syncthreads();
  if (t==0){
    pstat[(g*8+p)*2  ] = rs[0]+rs[1]+rs[2]+rs[3];
    pstat[(g*8+p)*2+1] = rss[0]+rss[1]+rss[2]+rss[3];
  }
}

// ---------------- GroupNorm apply + transpose to X[n][c]: grid (32, 16) ----------------
__global__ __launch_bounds__(256) void k_gn_apply(const float* __restrict__ x,
      const float* __restrict__ pstat, const float* __restrict__ gamma,
      const float* __restrict__ beta, u16* __restrict__ X){
  int g = blockIdx.x, c0 = g*16;
  int n = blockIdx.y*256 + threadIdx.x;
  float S=0.f, SS=0.f;
  #pragma unroll
  for (int p=0;p<8;p++){ S += pstat[(g*8+p)*2]; SS += pstat[(g*8+p)*2+1]; }
  float mean = S*(1.f/65536.f);
  float rstd = rsqrtf(SS*(1.f/65536.f) - mean*mean + EPS);
  u16 ov[16];
  #pragma unroll
  for (int c=0;c<16;c++){
    float gm = gamma[c0+c]*rstd;
    float be = beta[c0+c] - mean*gm;
    float v  = x[(size_t)(c0+c)*N_TOK + n]*gm + be;
    ov[c] = f2bf(v);
  }
  uint4* dst = (uint4*)&X[(size_t)n*C_DIM + c0];
  dst[0] = *(uint4*)&ov[0];
  dst[1] = *(uint4*)&ov[8];
}

// ---------------- fused QKV NT GEMM (V written transposed), grid 1536 ----------------
__global__ __launch_bounds__(256) void k_qkv(const u16* __restrict__ X,
      const u16* __restrict__ wq, const u16* __restrict__ wk,
      const u16* __restrict__ wv, u16* __restrict__ Qo, u16* __restrict__ Ko,
      u16* __restrict__ Vto){
  int b = blockIdx.x; int which = b >> 9; int r = b & 511;
  const u16 *A, *B; u16* Co; int ldc, m0, n0; float sc = 1.f;
  if (which==0){ A=X;  B=wq; Co=Qo;  ldc=512;  m0=(r>>3)*64; n0=(r&7)*64; sc=0.125f; }
  else if (which==1){ A=X;  B=wk; Co=Ko;  ldc=512;  m0=(r>>3)*64; n0=(r&7)*64; }
  else              { A=wv; B=X;  Co=Vto; ldc=4096; m0=(r>>6)*64; n0=(r&63)*64; }
  int t = threadIdx.x, w = t>>6, l = t&63, lr = l&15, li = l>>4;
  f32x4 acc[4] = {};
  const u16* Ap = A + (size_t)(m0 + w*16 + lr)*512 + li*8;
  const u16* Bp = B + (size_t)(n0 + lr)*512 + li*8;
  #pragma unroll
  for (int c=0;c<16;c++){
    bf16x8 a = *(const bf16x8*)(Ap + c*32);
    #pragma unroll
    for (int T=0;T<4;T++){
      bf16x8 bb = *(const bf16x8*)(Bp + (size_t)T*16*512 + c*32);
      acc[T] = __builtin_amdgcn_mfma_f32_16x16x32_bf16(a, bb, acc[T], 0,0,0);
    }
  }
  #pragma unroll
  for (int T=0;T<4;T++){
    #pragma unroll
    for (int j=0;j<4;j++){
      int mm = m0 + w*16 + li*4 + j;
      int nn = n0 + T*16 + lr;
      Co[(size_t)mm*ldc + nn] = f2bf(acc[T][j]*sc);
    }
  }
}

// ---------------- Flash attention: barrier-free, LDS only for P ----------------
// grid (64 q-tiles, 8 heads), block 256 = 4 independent waves x 16 q-rows
__global__ __launch_bounds__(256) void k_attn2(const u16* __restrict__ Q,
      const u16* __restrict__ K, const u16* __restrict__ Vt, u16* __restrict__ O){
  __shared__ u16 Pl[4*16*64];           // per-wave 2KB P tile [q][kk], swizzled
  int h  = blockIdx.y;
  int q0 = blockIdx.x*64;
  int t = threadIdx.x, w = t>>6, l = t&63, lr = l&15, li = l>>4;
  char* Plb = (char*)Pl + w*2048;

  const u16* Qp = Q + (size_t)(q0 + w*16 + lr)*512 + h*64 + li*8;
  bf16x8 qa0 = *(const bf16x8*)(Qp);
  bf16x8 qa1 = *(const bf16x8*)(Qp + 32);

  // B-frag bases: K[krow][d] rows stride 512; Vt[d][tok] rows stride 4096
  const u16* Kp = K  + (size_t)lr*512 + h*64 + li*8;
  const u16* Vp = Vt + (size_t)(h*64 + lr)*4096 + li*8;

  f32x4 acc[4] = {};
  float mrun[4] = {-1e30f,-1e30f,-1e30f,-1e30f};
  float lrun[4] = {0.f,0.f,0.f,0.f};

  for (int kb=0; kb<64; kb++){
    // ---- S = Q K^T (scale pre-folded into Q) ----
    const u16* Kk = Kp + (size_t)kb*64*512;
    f32x4 s[4] = {};
    __builtin_amdgcn_s_setprio(1);
    #pragma unroll
    for (int T=0;T<4;T++){
      bf16x8 b0 = *(const bf16x8*)(Kk + (size_t)T*16*512);
      bf16x8 b1 = *(const bf16x8*)(Kk + (size_t)T*16*512 + 32);
      s[T] = __builtin_amdgcn_mfma_f32_16x16x32_bf16(qa0, b0, s[T], 0,0,0);
      s[T] = __builtin_amdgcn_mfma_f32_16x16x32_bf16(qa1, b1, s[T], 0,0,0);
    }
    __builtin_amdgcn_s_setprio(0);

    // ---- online softmax per output row j ----
    #pragma unroll
    for (int j=0;j<4;j++){
      float tm = fmaxf(fmaxf(s[0][j],s[1][j]), fmaxf(s[2][j],s[3][j]));
      tm = fmaxf(tm, __shfl_xor(tm,1));
      tm = fmaxf(tm, __shfl_xor(tm,2));
      tm = fmaxf(tm, __shfl_xor(tm,4));
      tm = fmaxf(tm, __shfl_xor(tm,8));
      float mnew = fmaxf(mrun[j], tm);
      float fac  = __expf(mrun[j]-mnew);
      float p0=__expf(s[0][j]-mnew), p1=__expf(s[1][j]-mnew);
      float p2=__expf(s[2][j]-mnew), p3=__expf(s[3][j]-mnew);
      float ps = p0+p1+p2+p3;
      ps += __shfl_xor(ps,1); ps += __shfl_xor(ps,2);
      ps += __shfl_xor(ps,4); ps += __shfl_xor(ps,8);
      lrun[j] = lrun[j]*fac + ps;
      mrun[j] = mnew;
      #pragma unroll
      for (int T=0;T<4;T++) acc[T][j] *= fac;
      int prow = li*4 + j;
      u32 base = (u32)prow*128;
      int swz = (prow&7)<<4;
      *(u16*)(Plb + base + (((lr   )*2) ^ swz)) = f2bf(p0);
      *(u16*)(Plb + base + (((lr+16)*2) ^ swz)) = f2bf(p1);
      *(u16*)(Plb + base + (((lr+32)*2) ^ swz)) = f2bf(p2);
      *(u16*)(Plb + base + (((lr+48)*2) ^ swz)) = f2bf(p3);
    }

    // ---- acc += P @ V  (A = P from per-wave LDS, B = Vt rows from global) ----
    #pragma unroll
    for (int c=0;c<2;c++){
      int pswz = (lr&7)<<4;
      bf16x8 pa = *(const bf16x8*)(Plb + lr*128 + ((li*16 + c*64) ^ pswz));
      __builtin_amdgcn_s_setprio(1);
      #pragma unroll
      for (int T=0;T<4;T++){
        bf16x8 vb = *(const bf16x8*)(Vp + (size_t)T*16*4096 + kb*64 + c*32);
        acc[T] = __builtin_amdgcn_mfma_f32_16x16x32_bf16(pa, vb, acc[T], 0,0,0);
      }
      __builtin_amdgcn_s_setprio(0);
    }
  }

  // ---- epilogue: O[q][h*64+d] = acc / l ----
  #pragma unroll
  for (int j=0;j<4;j++){
    float inv = 1.f/lrun[j];
    #pragma unroll
    for (int T=0;T<4;T++){
      int r  = q0 + w*16 + li*4 + j;
      int cc = h*64 + T*16 + lr;
      O[(size_t)r*512 + cc] = f2bf(acc[T][j]*inv);
    }
  }
}

// ---------------- out-proj (computed transposed: y^T[c][n]) + bias + residual ----------------
// grid (8, 64), block 256
__global__ __launch_bounds__(256) void k_oproj(const u16* __restrict__ Wo,
      const u16* __restrict__ Ob, const float* __restrict__ bo,
      const float* __restrict__ res, float* __restrict__ out){
  int c0 = blockIdx.x*64, n0 = blockIdx.y*64;
  int t = threadIdx.x, w = t>>6, l = t&63, lr = l&15, li = l>>4;
  f32x4 acc[4] = {};
  const u16* Ap = Wo + (size_t)(c0 + w*16 + lr)*512 + li*8;
  const u16* Bp = Ob + (size_t)(n0 + lr)*512 + li*8;
  #pragma unroll
  for (int c=0;c<16;c++){
    bf16x8 a = *(const bf16x8*)(Ap + c*32);
    #pragma unroll
    for (int T=0;T<4;T++){
      bf16x8 b = *(const bf16x8*)(Bp + (size_t)T*16*512 + c*32);
      acc[T] = __builtin_amdgcn_mfma_f32_16x16x32_bf16(a, b, acc[T], 0,0,0);
    }
  }
  #pragma unroll
  for (int j=0;j<4;j++){
    int cc = c0 + w*16 + li*4 + j;
    float bias = bo[cc];
    #pragma unroll
    for (int T=0;T<4;T++){
      int nn = n0 + T*16 + lr;
      size_t off = (size_t)cc*4096 + nn;
      out[off] = acc[T][j] + bias + res[off];
    }
  }
}

extern "C" void kernel_launch(void* const* d_in, const int* in_sizes, int n_in,
                              void* d_out, int out_size, void* d_ws, size_t ws_size,
                              hipStream_t stream){
  (void)in_sizes; (void)n_in; (void)out_size; (void)ws_size;
  const float* hs    = (const float*)d_in[0];
  const float* gamma = (const float*)d_in[1];
  const float* beta  = (const float*)d_in[2];
  const float* wq    = (const float*)d_in[3];
  const float* wk    = (const float*)d_in[4];
  const float* wv    = (const float*)d_in[5];
  const float* wo    = (const float*)d_in[6];
  const float* bo    = (const float*)d_in[7];
  float* out = (float*)d_out;

  u16* X   = (u16*)d_ws;               // 4096*512
  u16* Qb  = X   + (size_t)4096*512;
  u16* Kb  = Qb  + (size_t)4096*512;
  u16* Vtb = Kb  + (size_t)4096*512;   // transposed V [512][4096]
  u16* Ob  = Vtb + (size_t)4096*512;
  u16* wqb = Ob  + (size_t)4096*512;
  u16* wkb = wqb + (size_t)512*512;
  u16* wvb = wkb + (size_t)512*512;
  u16* wob = wvb + (size_t)512*512;
  float* pstat = (float*)(wob + (size_t)512*512);   // 512 floats

  k_cvt4<<<1024,256,0,stream>>>(wq, wk, wv, wo, wqb, wkb, wvb, wob);
  dim3 gs(32, 8);
  k_gn_stats<<<gs,256,0,stream>>>(hs, pstat);
  dim3 ga(32, 16);
  k_gn_apply<<<ga,256,0,stream>>>(hs, pstat, gamma, beta, X);
  k_qkv<<<1536,256,0,stream>>>(X, wqb, wkb, wvb, Qb, Kb, Vtb);
  dim3 gat(64, 8);
  k_attn2<<<gat,256,0,stream>>>(Qb, Kb, Vtb, Ob);
  dim3 go(8, 64);
  k_oproj<<<go,256,0,stream>>>(wob, Ob, bo, hs, out);
}